// Round 19
// baseline (95.464 us; speedup 1.0000x reference)
//
#include <hip/hip_runtime.h>
#include <hip/hip_bf16.h>

// InvButterflyLayer via MFMA (bf16 in, fp32 accum). B=256, MID=16384, C=16.
// Live cone: level lvl needs t < 2^(8-lvl); lvl0 t<256 -> x[0:8224).
//
// R19: MEASUREMENT ROUND (kernels byte-identical to R18, but B2 and C2 bodies
// repeat x8 with asm-laundered pointers so the compiler re-executes honestly).
//   dur - 35.9 = 7*(T_B2 + T_C2); each rep-kernel = 8x its true cost ->
//   should enter rocprof top-5 WITH counters (first since R10).
// Idempotent: S7/out rewritten with identical values each rep.

#define OUT_HALF 2097152

typedef __attribute__((ext_vector_type(4))) float f32x4;
typedef __attribute__((ext_vector_type(8))) short s16x8;

extern __shared__ char smb[];

__device__ __forceinline__ uint fsw(uint a) {
    return a ^ ((((a >> 6) ^ (a >> 8)) & 3u) << 4);
}
__device__ __forceinline__ ushort bfr(float f) {
    __hip_bfloat16 h = __float2bfloat16(f);
    union { __hip_bfloat16 h; ushort u; } cv; cv.h = h; return cv.u;
}
__device__ __forceinline__ uint pk(float a, float b) {
    return (uint)bfr(a) | ((uint)bfr(b) << 16);
}

// W_T frag: lane(m=d, kg): k2 = kg*8.. as 4 packed uints  [verified R11-R18]
#define LDFRAG(dst, fb)                                                      \
    {                                                                        \
        const float* s_ = (fb) + m;                                          \
        _Pragma("unroll")                                                    \
        for (int cq_ = 0; cq_ < 4; cq_++) {                                  \
            int c_ = kg * 4 + cq_;                                           \
            (&(dst).x)[cq_] = pk(s_[c_ * 16], s_[256 + c_ * 16]);            \
        }                                                                    \
    }
// pack D (rows kg*4+reg, pairs) into next-level A rows  [verified R13-R18]
#define PACKW(baseoff, r2)                                                              \
    *(uint*)(smb + fsw((uint)((baseoff) + (r2) * 64 + m * 4))) =                        \
        pk(fmaxf(acc.x, 0.f), fmaxf(acc.y, 0.f));                                       \
    *(uint*)(smb + fsw((uint)((baseoff) + ((r2) + 1) * 64 + m * 4))) =                  \
        pk(fmaxf(acc.z, 0.f), fmaxf(acc.w, 0.f));

// ============ Kernel A: lvl0-3, wave-private (identical to R16-R18) ============
// LDS: X@0[4224] PA@4224[2048] PB@6272[2x1024] PC@8320[4x512] size 11392
__global__ __launch_bounds__(64, 2)
void ibf_A(const float* __restrict__ in_data, const float* __restrict__ mid_dense,
           const float* __restrict__ in_filter, const float* __restrict__ in_bias,
           const float* __restrict__ filters, const float* __restrict__ biases,
           uint* __restrict__ S3)
{
    const int lane = threadIdx.x;
    const int m = lane & 15, kg = lane >> 4;
    const int b = blockIdx.x;
    const int i = blockIdx.y >> 2;
    const int w = blockIdx.y & 3;

    {
        const float4* inb = (const float4*)in_data + (size_t)b * 8192 + (size_t)w * 1024;
        const float4* mdb = (const float4*)mid_dense + (size_t)w * 1024;
        for (int ip = lane; ip < 1040; ip += 64) {
            float4 iv = inb[ip], mv = mdb[ip];
            float xa = i ? iv.y * mv.y : iv.x * mv.x;
            float xb = i ? iv.w * mv.w : iv.z * mv.z;
            *(uint*)(smb + fsw((uint)(ip * 4))) = pk(xa, xb);
        }
    }
    s16x8 b0f, b1f;
#pragma unroll
    for (int j = 0; j < 8; j++) {
        b0f[j] = (short)bfr(in_filter[(kg * 8 + j) * 16 + m]);
        b1f[j] = (short)bfr(in_filter[(32 + kg * 8 + j) * 16 + m]);
    }
    float bv0 = in_bias[m];
    uint4 w1[2]; float bv1[2];
#pragma unroll
    for (int n = 0; n < 2; n++) {
        LDFRAG(w1[n], filters + (size_t)n * 512);
        bv1[n] = biases[n * 16 + m];
    }
    uint4 w2[4]; float bv2[4];
#pragma unroll
    for (int n = 0; n < 4; n++) {
        LDFRAG(w2[n], filters + 131072 + (size_t)n * 512);
        bv2[n] = biases[4096 + n * 16 + m];
    }
    uint4 w3[8]; float bv3[8];
#pragma unroll
    for (int n = 0; n < 8; n++) {
        LDFRAG(w3[n], filters + 2 * 131072 + (size_t)n * 512);
        bv3[n] = biases[2 * 4096 + n * 16 + m];
    }

#pragma unroll
    for (int tc = 0; tc < 4; tc++) {
        s16x8 a0 = *(const s16x8*)(smb + fsw((uint)((tc * 16 + m) * 64 + kg * 16)));
        s16x8 a1 = *(const s16x8*)(smb + fsw((uint)((tc * 16 + m) * 64 + 64 + kg * 16)));
        f32x4 acc = {bv0, bv0, bv0, bv0};
        acc = __builtin_amdgcn_mfma_f32_16x16x32_bf16(a0, b0f, acc, 0, 0, 0);
        acc = __builtin_amdgcn_mfma_f32_16x16x32_bf16(a1, b1f, acc, 0, 0, 0);
        const int r2 = tc * 8 + kg * 2;
        PACKW(4224, r2);
    }
#pragma unroll
    for (int tc = 0; tc < 2; tc++) {
        s16x8 af = *(const s16x8*)(smb + fsw((uint)(4224 + (tc * 16 + m) * 64 + kg * 16)));
#pragma unroll
        for (int s = 0; s < 2; s++) {
            f32x4 acc = {bv1[s], bv1[s], bv1[s], bv1[s]};
            acc = __builtin_amdgcn_mfma_f32_16x16x32_bf16(af, *(const s16x8*)&w1[s], acc, 0, 0, 0);
            const int r2 = tc * 8 + kg * 2;
            PACKW(6272 + s * 1024, r2);
        }
    }
#pragma unroll
    for (int p = 0; p < 2; p++) {
        s16x8 af = *(const s16x8*)(smb + fsw((uint)(6272 + p * 1024 + m * 64 + kg * 16)));
#pragma unroll
        for (int s = 0; s < 2; s++) {
            const int nl = 2 * p + s;
            f32x4 acc = {bv2[nl], bv2[nl], bv2[nl], bv2[nl]};
            acc = __builtin_amdgcn_mfma_f32_16x16x32_bf16(af, *(const s16x8*)&w2[nl], acc, 0, 0, 0);
            const int r2 = kg * 2;
            PACKW(8320 + nl * 512, r2);
        }
    }
    const int bi = 2 * b + i;
#pragma unroll
    for (int p = 0; p < 4; p++) {
        s16x8 af = *(const s16x8*)(smb + fsw((uint)(8320 + p * 512 + m * 64 + kg * 16)));
#pragma unroll
        for (int s = 0; s < 2; s++) {
            const int nl = 2 * p + s;
            f32x4 acc = {bv3[nl], bv3[nl], bv3[nl], bv3[nl]};
            acc = __builtin_amdgcn_mfma_f32_16x16x32_bf16(af, *(const s16x8*)&w3[nl], acc, 0, 0, 0);
            if (kg < 2) {
                const uint idx = ((uint)(nl * 512 + bi) * 16 + (uint)(4 * w + kg * 2)) * 16 + m;
                S3[idx]      = pk(fmaxf(acc.x, 0.f), fmaxf(acc.y, 0.f));
                S3[idx + 16] = pk(fmaxf(acc.z, 0.f), fmaxf(acc.w, 0.f));
            }
        }
    }
}

// ===== Kernel B2rep: R18-B2 body x8 (laundered) =====
// LDS: PA@0[2048] PB@2048[2x1024] PC@4096[4x512]  size 6144
__global__ __launch_bounds__(64, 2)
void ibf_B2(const float* __restrict__ filters, const float* __restrict__ biases,
            const uint* __restrict__ S3, uint* __restrict__ S7u)
{
    const int lane = threadIdx.x;
    const int m = lane & 15, kg = lane >> 4;
    const int n3 = blockIdx.x;
    const int c4 = blockIdx.y >> 1;
    const int n4 = 2 * n3 + (blockIdx.y & 1);
    const int bi0 = c4 * 4;

    uint loff = 0;
#pragma unroll 1
    for (int rep = 0; rep < 8; rep++) {
        asm volatile("" : "+v"(loff));            // opaque 0: defeats CSE/DSE
        const float* flt = filters + loff;
        const float* bia = biases + loff;
        const uint*  S3r = S3 + loff;
        uint*        S7r = S7u + loff;

        uint4 f4; float bv4;
        LDFRAG(f4, flt + 3 * 131072 + (size_t)n4 * 512);
        bv4 = bia[3 * 4096 + n4 * 16 + m];
        uint4 f5[2]; float bv5[2];
#pragma unroll
        for (int n = 0; n < 2; n++) {
            LDFRAG(f5[n], flt + 4 * 131072 + (size_t)(2 * n4 + n) * 512);
            bv5[n] = bia[4 * 4096 + (2 * n4 + n) * 16 + m];
        }
        uint4 f6[4]; float bv6[4];
#pragma unroll
        for (int n = 0; n < 4; n++) {
            LDFRAG(f6[n], flt + 5 * 131072 + (size_t)(4 * n4 + n) * 512);
            bv6[n] = bia[5 * 4096 + (4 * n4 + n) * 16 + m];
        }
        uint4 f7[8]; float bv7[8];
#pragma unroll
        for (int n = 0; n < 8; n++) {
            LDFRAG(f7[n], flt + 6 * 131072 + (size_t)(8 * n4 + n) * 512);
            bv7[n] = bia[6 * 4096 + (8 * n4 + n) * 16 + m];
        }

        // lvl4: A-frags DIRECT from S3 -> PA
#pragma unroll
        for (int tc = 0; tc < 4; tc++) {
            const char* rb = (const char*)S3r + (size_t)(n3 * 512 + bi0 + tc) * 1024;
            s16x8 af = *(const s16x8*)(rb + m * 64 + kg * 16);
            f32x4 acc = {bv4, bv4, bv4, bv4};
            acc = __builtin_amdgcn_mfma_f32_16x16x32_bf16(af, *(const s16x8*)&f4, acc, 0, 0, 0);
            const int r2 = tc * 8 + kg * 2;
            PACKW(0, r2);
        }
        // lvl5: PA -> PB
#pragma unroll
        for (int tc = 0; tc < 2; tc++) {
            s16x8 af = *(const s16x8*)(smb + fsw((uint)((tc * 16 + m) * 64 + kg * 16)));
#pragma unroll
            for (int s = 0; s < 2; s++) {
                f32x4 acc = {bv5[s], bv5[s], bv5[s], bv5[s]};
                acc = __builtin_amdgcn_mfma_f32_16x16x32_bf16(af, *(const s16x8*)&f5[s], acc, 0, 0, 0);
                const int r2 = tc * 8 + kg * 2;
                PACKW(2048 + s * 1024, r2);
            }
        }
        // lvl6: PB -> PC
#pragma unroll
        for (int p = 0; p < 2; p++) {
            s16x8 af = *(const s16x8*)(smb + fsw((uint)(2048 + p * 1024 + m * 64 + kg * 16)));
#pragma unroll
            for (int s = 0; s < 2; s++) {
                const int nl = 2 * p + s;
                f32x4 acc = {bv6[nl], bv6[nl], bv6[nl], bv6[nl]};
                acc = __builtin_amdgcn_mfma_f32_16x16x32_bf16(af, *(const s16x8*)&f6[nl], acc, 0, 0, 0);
                const int r2 = kg * 2;
                PACKW(4096 + nl * 512, r2);
            }
        }
        // lvl7: PC -> S7 global rows (valid kg<2), 64B rows
#pragma unroll
        for (int p = 0; p < 4; p++) {
            s16x8 af = *(const s16x8*)(smb + fsw((uint)(4096 + p * 512 + m * 64 + kg * 16)));
#pragma unroll
            for (int s = 0; s < 2; s++) {
                const int nl = 2 * p + s;
                f32x4 acc = {bv7[nl], bv7[nl], bv7[nl], bv7[nl]};
                acc = __builtin_amdgcn_mfma_f32_16x16x32_bf16(af, *(const s16x8*)&f7[nl], acc, 0, 0, 0);
                if (kg < 2) {
                    const uint n7g = (uint)(8 * n4 + nl);
                    const uint idx = ((n7g * 512u + (uint)(bi0 + kg * 2)) * 16u) + (uint)m;
                    S7r[idx]      = pk(fmaxf(acc.x, 0.f), fmaxf(acc.y, 0.f));
                    S7r[idx + 16] = pk(fmaxf(acc.z, 0.f), fmaxf(acc.w, 0.f));
                }
            }
        }
    }
}

// ===== Kernel C2rep: R18-C2 body x8 (laundered) =====
// LDS: 4 waves x 512B = 2048.
__global__ __launch_bounds__(256, 4)
void ibf_C2(const float* __restrict__ fea_dense, const float* __restrict__ filters,
            const float* __restrict__ biases, const uint* __restrict__ S7u,
            float* __restrict__ out)
{
    const int tid = threadIdx.x, lane = tid & 63, wave = tid >> 6;
    const int m = lane & 15, kg = lane >> 4;
    const int n8 = blockIdx.x;
    const int half = blockIdx.y;
    const int n7 = n8 >> 1;
    const float inv = 1.f / 16384.f;
    char* FT = smb + wave * 512;

    uint loff = 0;
#pragma unroll 1
    for (int rep = 0; rep < 8; rep++) {
        asm volatile("" : "+v"(loff));
        const float* fea = fea_dense + loff;
        const float* flt = filters + loff;
        const float* bia = biases + loff;
        const uint*  S7r = S7u + loff;
        float*       outr = out + loff;

        s16x8 afr[4];
#pragma unroll
        for (int ut = 0; ut < 4; ut++) afr[ut] = (s16x8){0, 0, 0, 0, 0, 0, 0, 0};
        if (kg < 2) {
            const float* fp = fea + (size_t)n8 * 1024 + (size_t)(kg * 8) * 64 + m;
#pragma unroll
            for (int ut = 0; ut < 4; ut++)
#pragma unroll
                for (int j = 0; j < 8; j++)
                    afr[ut][j] = (short)bfr(fp[ut * 16 + j * 64]);
        }
        uint4 f8;
        LDFRAG(f8, flt + 7 * 131072 + (size_t)n8 * 512);
        const float bv8 = bia[7 * 4096 + n8 * 16 + m];
        const int gj0 = n8 * 32;

        const int tb0 = half * 256 + wave * 64;
        s16x8 a8c = *(const s16x8*)((const char*)S7r +
                       (size_t)(n7 * 512 + tb0 + m) * 64 + kg * 16);
#pragma unroll
        for (int tl = 0; tl < 4; tl++) {
            const int tb = tb0 + tl * 16;
            s16x8 a8n;
            if (tl < 3)
                a8n = *(const s16x8*)((const char*)S7r +
                         (size_t)(n7 * 512 + tb + 16 + m) * 64 + kg * 16);
            {
                f32x4 acc = {bv8, bv8, bv8, bv8};
                acc = __builtin_amdgcn_mfma_f32_16x16x32_bf16(a8c, *(const s16x8*)&f8, acc, 0, 0, 0);
                float v[4] = {fmaxf(acc.x, 0.f), fmaxf(acc.y, 0.f),
                              fmaxf(acc.z, 0.f), fmaxf(acc.w, 0.f)};
#pragma unroll
                for (int j = 0; j < 4; j++)
                    *(ushort*)(FT + (kg * 4 + j) * 32 + m * 2) = bfr(v[j]);
            }
            s16x8 bf = {0, 0, 0, 0, 0, 0, 0, 0};
            if (kg < 2) bf = *(const s16x8*)(FT + m * 32 + kg * 16);
            const bool evenm = ((m & 1) == 0);
            const int b0 = (tb + m) >> 1;
#pragma unroll
            for (int ut = 0; ut < 4; ut++) {
                f32x4 acc = {0.f, 0.f, 0.f, 0.f};
                acc = __builtin_amdgcn_mfma_f32_16x16x32_bf16(afr[ut], bf, acc, 0, 0, 0);
                float sy = __shfl_xor(acc.y, 1);
                float sw = __shfl_xor(acc.w, 1);
                if (evenm) {
                    const int j = gj0 + ut * 8 + kg * 2;
                    *(float2*)(outr + (size_t)b0 * 8192 + j) =
                        make_float2((acc.x - sy) * inv, (acc.z - sw) * inv);
                    *(float2*)(outr + OUT_HALF + (size_t)b0 * 8192 + j) =
                        make_float2(acc.y, acc.w);
                }
            }
            a8c = a8n;
        }
    }
}

extern "C" void kernel_launch(void* const* d_in, const int* in_sizes, int n_in,
                              void* d_out, int out_size, void* d_ws, size_t ws_size,
                              hipStream_t stream) {
    const float* in_data   = (const float*)d_in[0];
    const float* mid_dense = (const float*)d_in[1];
    const float* in_filter = (const float*)d_in[2];
    const float* in_bias   = (const float*)d_in[3];
    const float* filters   = (const float*)d_in[4];
    const float* biases    = (const float*)d_in[5];
    const float* fea_dense = (const float*)d_in[6];
    float* out = (float*)d_out;
    uint* S3   = (uint*)d_ws;                        // 4 MB
    uint* S7u  = (uint*)((char*)d_ws + (4 << 20));   // 4 MB

    ibf_A<<<dim3(256, 8), 64, 11392, stream>>>(in_data, mid_dense, in_filter, in_bias,
                                               filters, biases, S3);
    ibf_B2<<<dim3(8, 256), 64, 6144, stream>>>(filters, biases, S3, S7u);
    ibf_C2<<<dim3(256, 2), 256, 2048, stream>>>(fea_dense, filters, biases, S7u, out);
}